// Round 15
// baseline (376.794 us; speedup 1.0000x reference)
//
#include <hip/hip_runtime.h>
#include <hip/hip_bf16.h>

typedef short v8s __attribute__((ext_vector_type(8)));
typedef float v4f __attribute__((ext_vector_type(4)));

#define MFMA16(a, b, c) __builtin_amdgcn_mfma_f32_16x16x32_bf16((a), (b), (c), 0, 0, 0)

constexpr int Bsz   = 128;
constexpr int Lq    = 32;
constexpr int Ld    = 512;
constexpr int H     = 768;
constexpr int D     = 128;
constexpr int QROWS = Bsz * Lq;          // 4096
constexpr int DROWS = Bsz * Ld;          // 65536
constexpr int NBQ   = QROWS / 16;        // 256 q blocks
constexpr int NBD   = DROWS / 16;        // 4096 doc groups per side

// f32 -> bf16 bits, round-to-nearest-even
static __device__ __forceinline__ unsigned short f2b(float f) {
    unsigned int u = __builtin_bit_cast(unsigned int, f);
    unsigned int r = u + 0x7FFFu + ((u >> 16) & 1u);
    return (unsigned short)(r >> 16);
}
static __device__ __forceinline__ v8s mk8(float4 f0, float4 f1) {
    v8s a;
    a[0] = (short)f2b(f0.x); a[1] = (short)f2b(f0.y);
    a[2] = (short)f2b(f0.z); a[3] = (short)f2b(f0.w);
    a[4] = (short)f2b(f1.x); a[5] = (short)f2b(f1.y);
    a[6] = (short)f2b(f1.z); a[7] = (short)f2b(f1.w);
    return a;
}

// ---------------------------------------------------------------------------
// Kernel 1: Wt[d][h] = bf16(W[h][d])
// ---------------------------------------------------------------------------
__global__ void prep_w_kernel(const float* __restrict__ W,
                              unsigned short* __restrict__ Wt) {
    int idx = blockIdx.x * 256 + threadIdx.x;
    if (idx < H * D) {
        int d = idx / H, h = idx % H;
        Wt[idx] = f2b(W[h * D + d]);
    }
}

// ---------------------------------------------------------------------------
// Kernel 1b: compact masks. One wave per (side, b): ascending index list of
// unmasked tokens + count. Deterministic (ballot + prefix popcount).
// ---------------------------------------------------------------------------
__global__ __launch_bounds__(64) void compact_kernel(
    const int* __restrict__ pdm, const int* __restrict__ ndm,
    int* __restrict__ idx, int* __restrict__ cnt)
{
    const int blk  = blockIdx.x;            // side*128 + b
    const int side = blk >> 7, b = blk & 127;
    const int lane = threadIdx.x;
    const int* m = (side ? ndm : pdm) + b * Ld;
    int* op = idx + (size_t)blk * Ld;

    int off = 0;
#pragma unroll
    for (int c = 0; c < Ld / 64; ++c) {
        const int t = c * 64 + lane;
        const bool p = (m[t] != 0);
        unsigned long long bal = __ballot(p);
        int pre = __popcll(bal & ((1ull << lane) - 1ull));
        if (p) op[off + pre] = t;
        off += __popcll(bal);
    }
    if (lane == 0) cnt[blk] = off;
}

// ---------------------------------------------------------------------------
// Kernel 2: projection — LDS-free, barrier-free K-loop, TLP-maximal.
//   Block = 16 rows x D=128; 4 waves = 4 col-slices (32 cols each); A-frag
//   loaded directly from global in MFMA layout (lane -> row ridx[l15],
//   k lg*8), W-frags from L2-hot Wt. acc = 8 VGPR/wave; launch_bounds(256,6)
//   -> 24 waves/CU; latency hidden by TLP (the R7-probe regime).
//   Doc blocks read compacted row lists; masked rows never touched.
//   Tail groups clamp-duplicate (idempotent). Epilogue: cross-wave L2-norm.
// ---------------------------------------------------------------------------
__global__ __launch_bounds__(256, 6) void proj_norm_kernel(
    const float* __restrict__ qh, const float* __restrict__ pdh,
    const float* __restrict__ ndh, const float* __restrict__ bias,
    const int* __restrict__ idx, const int* __restrict__ cnt,
    const unsigned short* __restrict__ Wt, unsigned short* __restrict__ emb)
{
    __shared__ int   ridx[16];     // source row within src tensor
    __shared__ int   eidx[16];     // emb row (fits in int: < 135168)
    __shared__ float ssred[4][16];

    const int tid  = threadIdx.x;
    const int lane = tid & 63, wave = tid >> 6;
    const int l15  = lane & 15, lg = lane >> 4;
    const int bid  = blockIdx.x;

    const float* src;
    if (bid < NBQ) {
        src = qh;
        if (tid < 16) {
            ridx[tid] = bid * 16 + tid;
            eidx[tid] = bid * 16 + tid;
        }
    } else {
        const int t    = bid - NBQ;
        const int side = t >> 12;            // 4096 groups per side
        const int g    = t & (NBD - 1);
        const int b    = g >> 5, lgr = g & 31;
        const int c    = cnt[side * 128 + b];
        if (lgr * 16 >= c) return;           // uniform: whole block exits
        src = side ? ndh : pdh;
        if (tid < 16) {
            int jj = lgr * 16 + tid;
            if (jj >= c) jj = c - 1;         // clamp-dup (idempotent store)
            const int tok = idx[(size_t)(side * 128 + b) * Ld + jj];
            ridx[tid] = b * Ld + tok;
            eidx[tid] = QROWS + side * DROWS + b * Ld + tok;
        }
    }
    __syncthreads();

    const float* ap = src + (size_t)ridx[l15] * H + lg * 8;
    const unsigned short* wp = Wt + (size_t)(wave * 32 + l15) * H + lg * 8;

    v4f acc0 = (v4f){0.f, 0.f, 0.f, 0.f};
    v4f acc1 = (v4f){0.f, 0.f, 0.f, 0.f};

#pragma unroll 2
    for (int kt = 0; kt < H / 32; ++kt) {
        float4 f0 = *(const float4*)(ap + kt * 32);
        float4 f1 = *(const float4*)(ap + kt * 32 + 4);
        v8s w0 = *(const v8s*)(wp + kt * 32);
        v8s w1 = *(const v8s*)(wp + (size_t)16 * H + kt * 32);
        v8s a  = mk8(f0, f1);
        acc0 = MFMA16(a, w0, acc0);
        acc1 = MFMA16(a, w1, acc1);
    }

    // ---- epilogue: bias, cross-wave L2-norm, store bf16 (no mask mult:
    //      only unmasked rows ever reach here) ----
    const float bv0 = bias[wave * 32 + l15];
    const float bv1 = bias[wave * 32 + 16 + l15];

    float ss[4];
#pragma unroll
    for (int q = 0; q < 4; ++q) {
        float v0 = acc0[q] + bv0;
        float v1 = acc1[q] + bv1;
        acc0[q] = v0; acc1[q] = v1;
        ss[q] = v0 * v0 + v1 * v1;
    }
#pragma unroll
    for (int off = 1; off < 16; off <<= 1)
#pragma unroll
        for (int q = 0; q < 4; ++q)
            ss[q] += __shfl_xor(ss[q], off);

    if (l15 == 0) {
#pragma unroll
        for (int q = 0; q < 4; ++q)
            ssred[wave][lg * 4 + q] = ss[q];
    }
    __syncthreads();

#pragma unroll
    for (int q = 0; q < 4; ++q) {
        const int row = lg * 4 + q;
        float t = ssred[0][row] + ssred[1][row] + ssred[2][row] + ssred[3][row];
        float s = 1.0f / fmaxf(sqrtf(t), 1e-12f);
        unsigned short* op = emb + (size_t)eidx[row] * D + wave * 32 + l15;
        op[0]  = f2b(acc0[q] * s);
        op[16] = f2b(acc1[q] * s);
    }
}

// ---------------------------------------------------------------------------
// Kernel 3: MaxSim over COMPACTED tokens. One block per (b, side); running
// max initialized to 0 iff any masked token exists (its score is exactly 0).
// ---------------------------------------------------------------------------
__global__ __launch_bounds__(256) void maxsim_kernel(
    const unsigned short* __restrict__ emb,
    const int* __restrict__ idx, const int* __restrict__ cnt,
    float* __restrict__ out)
{
    const int blk  = blockIdx.x;       // 0..255 : b*2 + side
    const int b    = blk >> 1, side = blk & 1;
    const int wave = threadIdx.x >> 6, lane = threadIdx.x & 63;
    const int l15  = lane & 15, lg = lane >> 4;

    const int c = cnt[side * 128 + b];
    const int* idxp = idx + (size_t)(side * 128 + b) * Ld;

    const unsigned short* Q  = emb + (size_t)(b * Lq) * D;
    const unsigned short* Dbase = emb + (size_t)(QROWS + side * DROWS + b * Ld) * D;

    // Q fragments: qa[m][kk], row m*16+l15, k kk*32+lg*8
    v8s qa[2][4];
#pragma unroll
    for (int m = 0; m < 2; ++m)
#pragma unroll
        for (int kk = 0; kk < 4; ++kk)
            qa[m][kk] = *(const v8s*)(Q + (size_t)(m * 16 + l15) * D + kk * 32 + lg * 8);

    const float minit = (c < Ld) ? 0.0f : -3.0e38f;
    float mx[2][4];
#pragma unroll
    for (int m = 0; m < 2; ++m)
#pragma unroll
        for (int q = 0; q < 4; ++q) mx[m][q] = minit;

    for (int j0 = wave * 16; j0 < c; j0 += 64) {
        int jj = j0 + l15;
        if (jj >= c) jj = c - 1;                    // dup: fmax-safe
        const int tok = idxp[jj];
        const unsigned short* dp = Dbase + (size_t)tok * D + lg * 8;
        v8s db0 = *(const v8s*)(dp);
        v8s db1 = *(const v8s*)(dp + 32);
        v8s db2 = *(const v8s*)(dp + 64);
        v8s db3 = *(const v8s*)(dp + 96);
#pragma unroll
        for (int m = 0; m < 2; ++m) {
            v4f a = (v4f){0.f, 0.f, 0.f, 0.f};
            a = MFMA16(qa[m][0], db0, a);
            a = MFMA16(qa[m][1], db1, a);
            a = MFMA16(qa[m][2], db2, a);
            a = MFMA16(qa[m][3], db3, a);
#pragma unroll
            for (int q = 0; q < 4; ++q) mx[m][q] = fmaxf(mx[m][q], a[q]);
        }
    }

    // reduce max over the 16 token-lanes
#pragma unroll
    for (int off = 1; off < 16; off <<= 1)
#pragma unroll
        for (int m = 0; m < 2; ++m)
#pragma unroll
            for (int q = 0; q < 4; ++q)
                mx[m][q] = fmaxf(mx[m][q], __shfl_xor(mx[m][q], off));

    __shared__ float red[4][32];
    if (l15 == 0) {
#pragma unroll
        for (int m = 0; m < 2; ++m)
#pragma unroll
            for (int q = 0; q < 4; ++q)
                red[wave][m * 16 + lg * 4 + q] = mx[m][q];
    }
    __syncthreads();

    if (threadIdx.x < 32) {
        const int q = threadIdx.x;
        float v = fmaxf(fmaxf(red[0][q], red[1][q]), fmaxf(red[2][q], red[3][q]));
#pragma unroll
        for (int off = 1; off < 32; off <<= 1) v += __shfl_xor(v, off);
        if (q == 0) out[blk] = v;
    }
}

// ---------------------------------------------------------------------------
extern "C" void kernel_launch(void* const* d_in, const int* in_sizes, int n_in,
                              void* d_out, int out_size, void* d_ws, size_t ws_size,
                              hipStream_t stream)
{
    const float* qh   = (const float*)d_in[0];
    const float* pdh  = (const float*)d_in[1];
    const float* ndh  = (const float*)d_in[2];
    const float* W    = (const float*)d_in[3];
    const float* bias = (const float*)d_in[4];
    const int*   pdm  = (const int*)d_in[5];
    const int*   ndm  = (const int*)d_in[6];
    float* out = (float*)d_out;

    // ws layout: Wt (192 KB) | idx (512 KB) | cnt (1 KB) | emb (34.6 MB)
    char* wsb = (char*)d_ws;
    unsigned short* Wt  = (unsigned short*)wsb;
    int*            idx = (int*)(wsb + 196608);
    int*            cnt = (int*)(wsb + 196608 + 524288);
    unsigned short* emb = (unsigned short*)(wsb + 196608 + 524288 + 1024);

    prep_w_kernel<<<(H * D + 255) / 256, 256, 0, stream>>>(W, Wt);
    compact_kernel<<<256, 64, 0, stream>>>(pdm, ndm, idx, cnt);
    proj_norm_kernel<<<NBQ + 2 * NBD, 256, 0, stream>>>(qh, pdh, ndh, bias,
                                                        idx, cnt, Wt, emb);
    maxsim_kernel<<<Bsz * 2, 256, 0, stream>>>(emb, idx, cnt, out);
}

// Round 16
// 105.246 us; speedup vs baseline: 3.5801x; 3.5801x over previous
//
#include <hip/hip_runtime.h>
#include <hip/hip_bf16.h>

typedef short v8s __attribute__((ext_vector_type(8)));
typedef float v4f __attribute__((ext_vector_type(4)));

#define MFMA16(a, b, c) __builtin_amdgcn_mfma_f32_16x16x32_bf16((a), (b), (c), 0, 0, 0)

typedef __attribute__((address_space(1))) const void g_void;
typedef __attribute__((address_space(3))) void lds_void;
#define GLOAD_LDS16(g, l) \
    __builtin_amdgcn_global_load_lds((g_void*)(g), (lds_void*)(l), 16, 0, 0)

constexpr int Bsz   = 128;
constexpr int Lq    = 32;
constexpr int Ld    = 512;
constexpr int H     = 768;
constexpr int D     = 128;
constexpr int QROWS = Bsz * Lq;          // 4096
constexpr int DROWS = Bsz * Ld;          // 65536
constexpr int BM    = 64;                // rows per block
constexpr int BK    = 64;                // K per tile
constexpr int NT    = H / BK;            // 12 K-tiles
constexpr int NQB   = QROWS / BM;        // 64 q blocks
constexpr int NDG   = (Ld / BM) * Bsz;   // 1024 doc groups per side

// f32 -> bf16 bits, round-to-nearest-even
static __device__ __forceinline__ unsigned short f2b(float f) {
    unsigned int u = __builtin_bit_cast(unsigned int, f);
    unsigned int r = u + 0x7FFFu + ((u >> 16) & 1u);
    return (unsigned short)(r >> 16);
}
static __device__ __forceinline__ unsigned int pack2(float a, float b) {
    return (unsigned int)f2b(a) | ((unsigned int)f2b(b) << 16);
}

// ---------------------------------------------------------------------------
// Kernel 1: Wt[d][h] = bf16(W[h][d])
// ---------------------------------------------------------------------------
__global__ void prep_w_kernel(const float* __restrict__ W,
                              unsigned short* __restrict__ Wt) {
    int idx = blockIdx.x * 256 + threadIdx.x;
    if (idx < H * D) {
        int d = idx / H, h = idx % H;
        Wt[idx] = f2b(W[h * D + d]);
    }
}

// ---------------------------------------------------------------------------
// Kernel 1b: compact masks. One wave per (side, b): ascending index list of
// unmasked tokens + count. Deterministic (ballot + prefix popcount).
// ---------------------------------------------------------------------------
__global__ __launch_bounds__(64) void compact_kernel(
    const int* __restrict__ pdm, const int* __restrict__ ndm,
    int* __restrict__ idx, int* __restrict__ cnt)
{
    const int blk  = blockIdx.x;            // side*128 + b
    const int side = blk >> 7, b = blk & 127;
    const int lane = threadIdx.x;
    const int* m = (side ? ndm : pdm) + b * Ld;
    int* op = idx + (size_t)blk * Ld;

    int off = 0;
#pragma unroll
    for (int c = 0; c < Ld / 64; ++c) {
        const int t = c * 64 + lane;
        const bool p = (m[t] != 0);
        unsigned long long bal = __ballot(p);
        int pre = __popcll(bal & ((1ull << lane) - 1ull));
        if (p) op[off + pre] = t;
        off += __popcll(bal);
    }
    if (lane == 0) cnt[blk] = off;
}

// ---------------------------------------------------------------------------
// Kernel 2: projection (R13-verified pipeline + compacted row gather).
//   A (HBM): register float4 loads, converted once to bf16, ds_write into
//   swizzled tile [64][64] bf16 (dbuf). W (L2): global_load_lds DMA.
//   Counted vmcnt, never drained mid-loop. Doc blocks process 64 UNMASKED
//   rows via compacted idx; blocks past count exit; tail clamp-duplicates
//   (idempotent stores). 4 waves: mg=row-half x ng=col-half.
// ---------------------------------------------------------------------------
__global__ __launch_bounds__(256, 4) void proj_norm_kernel(
    const float* __restrict__ qh, const float* __restrict__ pdh,
    const float* __restrict__ ndh, const float* __restrict__ bias,
    const int* __restrict__ idx, const int* __restrict__ cnt,
    const unsigned short* __restrict__ Wt, unsigned short* __restrict__ emb)
{
    __shared__ unsigned short Abuf[2][BM * BK];   // 2 x 8 KB bf16
    __shared__ unsigned short Wbuf[2][D * BK];    // 2 x 16 KB bf16
    __shared__ float ssred[2][BM];
    __shared__ int   ridx[BM];                    // gathered source rows
    __shared__ int   eidx[BM];                    // emb rows

    const int tid  = threadIdx.x;
    const int lane = tid & 63, wave = tid >> 6;
    const int l15  = lane & 15, lg = lane >> 4;
    const int mg   = wave >> 1;                   // row half (32 rows)
    const int ng   = wave & 1;                    // col half (64 cols)
    const int bid  = blockIdx.x;

    const float* src;
    if (bid < NQB) {
        src = qh;
        if (tid < BM) {
            ridx[tid] = bid * BM + tid;
            eidx[tid] = bid * BM + tid;
        }
    } else {
        const int t    = bid - NQB;
        const int side = t >> 10;                 // 1024 groups per side
        const int g    = t & (NDG - 1);
        const int b    = g >> 3, lgr = g & 7;
        const int c    = cnt[side * 128 + b];
        if (lgr * BM >= c) return;                // uniform block exit
        src = side ? ndh : pdh;
        if (tid < BM) {
            int jj = lgr * BM + tid;
            if (jj >= c) jj = c - 1;              // clamp-dup (idempotent)
            const int tok = idx[(size_t)(side * 128 + b) * Ld + jj];
            ridx[tid] = b * Ld + tok;
            eidx[tid] = QROWS + side * DROWS + b * Ld + tok;
        }
    }
    __syncthreads();

    // ---- A register staging: thread -> row rr (gathered), 64 contig bytes
    const int rr = tid >> 2;                      // 0..63
    const int cc = tid & 3;                       // 16-float sub-block
    const float* gA = src + (size_t)ridx[rr] * H + cc * 16;

    float4 rA[4];

    auto issueA = [&](int kt) {
#pragma unroll
        for (int j = 0; j < 4; ++j)
            rA[j] = *(const float4*)(gA + kt * BK + j * 4);
    };
    auto writeA = [&](int bi) {
#pragma unroll
        for (int j = 0; j < 4; ++j) {
            const int sl = (cc * 4 + j) ^ ((rr & 7) << 1);
            uint2 u;
            u.x = pack2(rA[j].x, rA[j].y);
            u.y = pack2(rA[j].z, rA[j].w);
            *(uint2*)(&Abuf[bi][rr * 64 + sl * 4]) = u;
        }
    };

    auto stageW = [&](int bi, int kt) {
#pragma unroll
        for (int i = 0; i < 4; ++i) {
            const int d  = 32 * wave + 8 * i + (lane >> 3);
            const int cw = (lane & 7) ^ (lane >> 3);
            const unsigned short* gp = Wt + (size_t)d * H + kt * BK + cw * 8;
            GLOAD_LDS16(gp, &Wbuf[bi][(32 * wave + 8 * i) * BK]);
        }
    };

    v4f acc[2][4];
#pragma unroll
    for (int mt = 0; mt < 2; ++mt)
#pragma unroll
        for (int nt = 0; nt < 4; ++nt) acc[mt][nt] = (v4f){0.f, 0.f, 0.f, 0.f};

    auto compute = [&](int bi) {
#pragma unroll
        for (int kk = 0; kk < 2; ++kk) {
            v8s wfr[4];
#pragma unroll
            for (int nt = 0; nt < 4; ++nt) {
                const int d  = ng * 64 + nt * 16 + l15;
                const int ch = (kk * 4 + lg) ^ (l15 & 7);
                wfr[nt] = *(const v8s*)(&Wbuf[bi][d * BK + ch * 8]);
            }
#pragma unroll
            for (int mt = 0; mt < 2; ++mt) {
                const int r  = mg * 32 + mt * 16 + l15;
                const int ch = (kk * 4 + lg) ^ (r & 7);
                v8s a = *(const v8s*)(&Abuf[bi][r * 64 + ch * 8]);
#pragma unroll
                for (int nt = 0; nt < 4; ++nt)
                    acc[mt][nt] = MFMA16(a, wfr[nt], acc[mt][nt]);
            }
        }
    };

    // ---- prologue: tile0 staged+written, tile1 in flight ----
    issueA(0); stageW(0, 0);                       // FIFO: A0(4), W0(4)
    asm volatile("s_waitcnt vmcnt(4)" ::: "memory");   // A0 regs ready
    writeA(0);
    issueA(1); stageW(1, 1);                       // FIFO: W0(4), A1(4), W1(4)
    asm volatile("s_waitcnt vmcnt(8)" ::: "memory");   // W0 done
    asm volatile("s_waitcnt lgkmcnt(0)" ::: "memory"); // A0 writes done
    __builtin_amdgcn_sched_barrier(0);
    __builtin_amdgcn_s_barrier();                  // tile0 ready

#pragma unroll
    for (int t = 0; t < NT; ++t) {
        compute(t & 1);
        if (t + 1 < NT) {
            __builtin_amdgcn_sched_barrier(0);
            asm volatile("s_waitcnt vmcnt(4)" ::: "memory");   // A(t+1) ready
            writeA((t + 1) & 1);
            if (t + 2 < NT) {
                issueA(t + 2);
                stageW(t & 1 /* == (t+2)&1 */, t + 2);
                asm volatile("s_waitcnt vmcnt(8)" ::: "memory"); // W(t+1) done
            } else {
                asm volatile("s_waitcnt vmcnt(0)" ::: "memory"); // tail drain
            }
            asm volatile("s_waitcnt lgkmcnt(0)" ::: "memory");   // my ds_writes
            __builtin_amdgcn_sched_barrier(0);
            __builtin_amdgcn_s_barrier();          // tile t+1 ready
        }
    }

    // ---- epilogue: bias, cross-ng L2-norm, store bf16 (no mask multiply:
    //      masked rows never reach here) ----
    float bv[4];
#pragma unroll
    for (int nt = 0; nt < 4; ++nt) bv[nt] = bias[ng * 64 + nt * 16 + l15];

    float ss[2][4];
#pragma unroll
    for (int mt = 0; mt < 2; ++mt)
#pragma unroll
        for (int q = 0; q < 4; ++q) {
            float s = 0.f;
#pragma unroll
            for (int nt = 0; nt < 4; ++nt) {
                float v = acc[mt][nt][q] + bv[nt];
                acc[mt][nt][q] = v;
                s += v * v;
            }
            ss[mt][q] = s;
        }
#pragma unroll
    for (int off = 1; off < 16; off <<= 1)
#pragma unroll
        for (int mt = 0; mt < 2; ++mt)
#pragma unroll
            for (int q = 0; q < 4; ++q)
                ss[mt][q] += __shfl_xor(ss[mt][q], off);

    if (l15 == 0) {
#pragma unroll
        for (int mt = 0; mt < 2; ++mt)
#pragma unroll
            for (int q = 0; q < 4; ++q)
                ssred[ng][mg * 32 + mt * 16 + lg * 4 + q] = ss[mt][q];
    }
    __syncthreads();

#pragma unroll
    for (int mt = 0; mt < 2; ++mt)
#pragma unroll
        for (int q = 0; q < 4; ++q) {
            const int row = mg * 32 + mt * 16 + lg * 4 + q;
            float t = ssred[0][row] + ssred[1][row];
            float s = 1.0f / fmaxf(sqrtf(t), 1e-12f);
            unsigned short* op = emb + (size_t)eidx[row] * D + ng * 64 + l15;
#pragma unroll
            for (int nt = 0; nt < 4; ++nt)
                op[nt * 16] = f2b(acc[mt][nt][q] * s);
        }
}

// ---------------------------------------------------------------------------
// Kernel 3: MaxSim over COMPACTED tokens (R15-verified). Max-init 0 iff any
// masked token exists (masked embeddings are exactly zero).
// ---------------------------------------------------------------------------
__global__ __launch_bounds__(256) void maxsim_kernel(
    const unsigned short* __restrict__ emb,
    const int* __restrict__ idx, const int* __restrict__ cnt,
    float* __restrict__ out)
{
    const int blk  = blockIdx.x;       // 0..255 : b*2 + side
    const int b    = blk >> 1, side = blk & 1;
    const int wave = threadIdx.x >> 6, lane = threadIdx.x & 63;
    const int l15  = lane & 15, lg = lane >> 4;

    const int c = cnt[side * 128 + b];
    const int* idxp = idx + (size_t)(side * 128 + b) * Ld;

    const unsigned short* Q  = emb + (size_t)(b * Lq) * D;
    const unsigned short* Dbase = emb + (size_t)(QROWS + side * DROWS + b * Ld) * D;

    v8s qa[2][4];
#pragma unroll
    for (int m = 0; m < 2; ++m)
#pragma unroll
        for (int kk = 0; kk < 4; ++kk)
            qa[m][kk] = *(const v8s*)(Q + (size_t)(m * 16 + l15) * D + kk * 32 + lg * 8);

    const float minit = (c < Ld) ? 0.0f : -3.0e38f;
    float mx[2][4];
#pragma unroll
    for (int m = 0; m < 2; ++m)
#pragma unroll
        for (int q = 0; q < 4; ++q) mx[m][q] = minit;

    for (int j0 = wave * 16; j0 < c; j0 += 64) {
        int jj = j0 + l15;
        if (jj >= c) jj = c - 1;                    // dup: fmax-safe
        const int tok = idxp[jj];
        const unsigned short* dp = Dbase + (size_t)tok * D + lg * 8;
        v8s db0 = *(const v8s*)(dp);
        v8s db1 = *(const v8s*)(dp + 32);
        v8s db2 = *(const v8s*)(dp + 64);
        v8s db3 = *(const v8s*)(dp + 96);
#pragma unroll
        for (int m = 0; m < 2; ++m) {
            v4f a = (v4f){0.f, 0.f, 0.f, 0.f};
            a = MFMA16(qa[m][0], db0, a);
            a = MFMA16(qa[m][1], db1, a);
            a = MFMA16(qa[m][2], db2, a);
            a = MFMA16(qa[m][3], db3, a);
#pragma unroll
            for (int q = 0; q < 4; ++q) mx[m][q] = fmaxf(mx[m][q], a[q]);
        }
    }

#pragma unroll
    for (int off = 1; off < 16; off <<= 1)
#pragma unroll
        for (int m = 0; m < 2; ++m)
#pragma unroll
            for (int q = 0; q < 4; ++q)
                mx[m][q] = fmaxf(mx[m][q], __shfl_xor(mx[m][q], off));

    __shared__ float red[4][32];
    if (l15 == 0) {
#pragma unroll
        for (int m = 0; m < 2; ++m)
#pragma unroll
            for (int q = 0; q < 4; ++q)
                red[wave][m * 16 + lg * 4 + q] = mx[m][q];
    }
    __syncthreads();

    if (threadIdx.x < 32) {
        const int q = threadIdx.x;
        float v = fmaxf(fmaxf(red[0][q], red[1][q]), fmaxf(red[2][q], red[3][q]));
#pragma unroll
        for (int off = 1; off < 32; off <<= 1) v += __shfl_xor(v, off);
        if (q == 0) out[blk] = v;
    }
}

// ---------------------------------------------------------------------------
extern "C" void kernel_launch(void* const* d_in, const int* in_sizes, int n_in,
                              void* d_out, int out_size, void* d_ws, size_t ws_size,
                              hipStream_t stream)
{
    const float* qh   = (const float*)d_in[0];
    const float* pdh  = (const float*)d_in[1];
    const float* ndh  = (const float*)d_in[2];
    const float* W    = (const float*)d_in[3];
    const float* bias = (const float*)d_in[4];
    const int*   pdm  = (const int*)d_in[5];
    const int*   ndm  = (const int*)d_in[6];
    float* out = (float*)d_out;

    // ws layout: Wt (192 KB) | idx (512 KB) | cnt (1 KB) | emb (34.6 MB)
    char* wsb = (char*)d_ws;
    unsigned short* Wt  = (unsigned short*)wsb;
    int*            idx = (int*)(wsb + 196608);
    int*            cnt = (int*)(wsb + 196608 + 524288);
    unsigned short* emb = (unsigned short*)(wsb + 196608 + 524288 + 1024);

    prep_w_kernel<<<(H * D + 255) / 256, 256, 0, stream>>>(W, Wt);
    compact_kernel<<<256, 64, 0, stream>>>(pdm, ndm, idx, cnt);
    proj_norm_kernel<<<NQB + 2 * NDG, 256, 0, stream>>>(qh, pdh, ndh, bias,
                                                        idx, cnt, Wt, emb);
    maxsim_kernel<<<Bsz * 2, 256, 0, stream>>>(emb, idx, cnt, out);
}